// Round 3
// baseline (6167.847 us; speedup 1.0000x reference)
//
#include <hip/hip_runtime.h>
#include <cstdint>
#include <cstddef>

// ---------------------------------------------------------------------------
// Trainer_91216515433187: BN + Dense + LSTM encoder (1024 steps) + 35-step
// autoregressive LSTM decoder.
//
// Round 4: one WG (512 thr, 8 waves) per 16 batch rows; ONE barrier per step
// (h double-buffered by parity, XOR base flip). Weight slots (8 x 32-k):
//   regs: slots 0,1,2 (96 VGPR)  |  LDS pool: slots 6,7 (128 KB)
//   L2 stream: slots 3,4,5 through ONE 32-reg buffer, consumed-then-refilled
//   (s3 prefetched in previous step; refills issued right after consumption
//   so every load has a >=900cy window; barrier drain only sees s3').
// Slot-8 affine (Weff enc / Deff dec) streamed from L2 per step, quad0-only.
// x loaded per-step from pulse by quad0 lanes (consumed at slot-8, end).
// Decoder: every wave computes pred redundantly (8 MFMAs vs WmlpT), token
// redistributed via intra-wave __shfl -> registers, no LDS staging.
// LDS: pool 131072 + h 2x8192 + zbias 4096 = 151552 B.
// ---------------------------------------------------------------------------

typedef _Float16 h8 __attribute__((ext_vector_type(8)));
typedef float f4 __attribute__((ext_vector_type(4)));

// ws byte offsets
#define WS_DEFFH  256       // 1024 x 8 f16 = 16384 (packed [Deff0,Deff1,0..])
#define WS_RKT    262400    // 1024 cols x 256 k f16 = 524288
#define WS_WEFF   786688    // 1024 cols x 8 f f16 = 16384
#define WS_WMLP   803072    // 2 e x 256 k f16 = 1024
#define WS_ZB     812288    // 1024 f32
#define WS_DB     816384    // 1024 f32

// LDS layout
#define LB_POOL  0          // slots 6,7: [w8][fi16][lane64]*16B = 131072
#define LB_H0    131072     // h parity buffers: 2 x 8192
#define LB_ZB    147456     // 1024 f32 = 4096
#define LDS_SZ   151552

__device__ __forceinline__ float fexp2(float x){
#if __has_builtin(__builtin_amdgcn_exp2f)
  return __builtin_amdgcn_exp2f(x);
#else
  return exp2f(x);
#endif
}
__device__ __forceinline__ float frcp(float x){
#if __has_builtin(__builtin_amdgcn_rcpf)
  return __builtin_amdgcn_rcpf(x);
#else
  return 1.f / x;
#endif
}
__device__ __forceinline__ float sigf(float x){
  return frcp(1.f + fexp2(-1.44269504f * x));
}
__device__ __forceinline__ float tanh_f(float x){
  return 2.f * frcp(1.f + fexp2(-2.88539008f * x)) - 1.f;
}

// grid 1024 x 256 threads
__global__ void precompute_k(const float* __restrict__ bn_gamma,
                             const float* __restrict__ bn_beta,
                             const float* __restrict__ bn_mean,
                             const float* __restrict__ bn_var,
                             const float* __restrict__ W_pulse,   // (8,256)
                             const float* __restrict__ b_pulse,   // (256)
                             const float* __restrict__ lstm_k,    // (256,1024)
                             const float* __restrict__ lstm_rk,   // (256,1024)
                             const float* __restrict__ lstm_b,    // (1024)
                             const float* __restrict__ W_eis,     // (2,256)
                             const float* __restrict__ b_eis,     // (256)
                             const float* __restrict__ W_mlp,     // (256,2)
                             _Float16* __restrict__ rkT,          // [col][k]
                             _Float16* __restrict__ WeffT,        // [col][f]
                             _Float16* __restrict__ WmlpT,        // [e][k]
                             _Float16* __restrict__ DeffH,        // [col][8]
                             float* __restrict__ zbias,
                             float* __restrict__ dbias)
{
  int gid = blockIdx.x * 256 + threadIdx.x;   // 0..262143
  {
    int col = gid >> 8;
    int k   = gid & 255;
    rkT[col * 256 + k] = (_Float16)lstm_rk[k * 1024 + col];
  }
  if (gid < 512) {
    int e = gid >> 8, k = gid & 255;
    WmlpT[e * 256 + k] = (_Float16)W_mlp[k * 2 + e];
  }
  if (gid < 1024) {
    int j = gid;
    float a[8], bv[8];
#pragma unroll
    for (int f = 0; f < 8; ++f) {
      float af = bn_gamma[f] * rsqrtf(bn_var[f] + 1e-3f);
      a[f]  = af;
      bv[f] = bn_beta[f] - bn_mean[f] * af;
    }
    float m[8] = {0,0,0,0,0,0,0,0};
    float d0 = 0.f, d1 = 0.f, zb2 = 0.f, db2 = 0.f;
    for (int k = 0; k < 256; ++k) {
      float lk = lstm_k[k * 1024 + j];
#pragma unroll
      for (int f = 0; f < 8; ++f) m[f] += W_pulse[f * 256 + k] * lk;
      d0  += W_eis[k]       * lk;
      d1  += W_eis[256 + k] * lk;
      zb2 += b_pulse[k] * lk;
      db2 += b_eis[k]   * lk;
    }
    float zb = lstm_b[j] + zb2;
#pragma unroll
    for (int f = 0; f < 8; ++f) {
      zb += bv[f] * m[f];
      WeffT[j * 8 + f] = (_Float16)(a[f] * m[f]);
    }
    zbias[j] = zb;
    dbias[j] = lstm_b[j] + db2;
    DeffH[j * 8 + 0] = (_Float16)d0;
    DeffH[j * 8 + 1] = (_Float16)d1;
#pragma unroll
    for (int f = 2; f < 8; ++f) DeffH[j * 8 + f] = (_Float16)0.f;
  }
}

// global weight frag: byte offset for (col = g*256+w*32+u*16+n, s8, quad)
#define GFRAG(s8_, u_, g_)                                                     \
  (*reinterpret_cast<const h8*>(                                               \
      rkTb + (gbo + (uint32_t)((g_) * 131072 + (u_) * 8192 + (s8_) * 64))))

#define LDH(s_) (*reinterpret_cast<const h8*>(&smem[h_rd + (uint32_t)((s_) * 1024)]))

#define MM(ha_, B_)                                                            \
  _Pragma("unroll") for (int u_ = 0; u_ < 2; ++u_)                             \
  _Pragma("unroll") for (int g_ = 0; g_ < 4; ++g_)                             \
    acc[u_][g_] = __builtin_amdgcn_mfma_f32_16x16x32_f16(                      \
        (ha_), (B_)[u_][g_], acc[u_][g_], 0, 0, 0);

#define MMH(ha_, P_, half_)                                                    \
  _Pragma("unroll") for (int g_ = 0; g_ < 4; ++g_)                             \
    acc[half_][g_] = __builtin_amdgcn_mfma_f32_16x16x32_f16(                   \
        (ha_), (P_)[g_], acc[half_][g_], 0, 0, 0);

#define GQLD(s8_)                                                              \
  _Pragma("unroll") for (int u_ = 0; u_ < 2; ++u_)                             \
  _Pragma("unroll") for (int g_ = 0; g_ < 4; ++g_)                             \
    gq[u_][g_] = GFRAG(s8_, u_, g_);

#define POOLLD(k_)                                                             \
  _Pragma("unroll") for (int i_ = 0; i_ < 4; ++i_)                             \
    pq[i_] = *reinterpret_cast<const h8*>(                                     \
        &smem[pool_rd + (uint32_t)(((k_) * 4 + i_) * 1024)]);

// full step: MFMA over 9 K-slots. P8B_ = slot-8 B base (Weff/Deff), PA_ = A code
#define WSTEP(P8B_, PA_CODE_)                                                  \
  {                                                                            \
    h8 a3 = LDH(3);                                                            \
    h8 a0 = LDH(0);                                                            \
    MM(a3, gq);              /* slot 3 (prefetched) */                         \
    GQLD(4);                                                                   \
    h8 p8a[4], p8b[4];                                                         \
    _Pragma("unroll") for (int g_ = 0; g_ < 4; ++g_) { p8a[g_] = z8; p8b[g_] = z8; } \
    if (quad == 0) {                                                           \
      _Pragma("unroll") for (int g_ = 0; g_ < 4; ++g_)                         \
        p8a[g_] = *reinterpret_cast<const h8*>((P8B_) + p8o + g_ * 4096);      \
    }                                                                          \
    __builtin_amdgcn_sched_barrier(0);                                         \
    h8 a1 = LDH(1); MM(a0, Wreg[0]);                                           \
    h8 a2 = LDH(2); MM(a1, Wreg[1]);                                           \
    h8 pq[4];                                                                  \
    POOLLD(0);                                                                 \
    h8 a6 = LDH(6); MM(a2, Wreg[2]);                                           \
    MMH(a6, pq, 0);                                                            \
    POOLLD(1);                                                                 \
    h8 a4 = LDH(4);                                                            \
    MMH(a6, pq, 1);                                                            \
    MM(a4, gq);              /* slot 4 */                                      \
    GQLD(5);                                                                   \
    h8 a7 = LDH(7);                                                            \
    POOLLD(2); MMH(a7, pq, 0);                                                 \
    POOLLD(3); MMH(a7, pq, 1);                                                 \
    if (quad == 0) {                                                           \
      _Pragma("unroll") for (int g_ = 0; g_ < 4; ++g_)                         \
        p8b[g_] = *reinterpret_cast<const h8*>((P8B_) + p8o + g_ * 4096 + 256);\
    }                                                                          \
    h8 a5 = LDH(5);                                                            \
    MM(a5, gq);              /* slot 5 */                                      \
    GQLD(3);                 /* prefetch next step */                          \
    __builtin_amdgcn_sched_barrier(0);                                         \
    h8 pa = z8;                                                                \
    PA_CODE_                                                                   \
    _Pragma("unroll") for (int g_ = 0; g_ < 4; ++g_)                           \
      acc[0][g_] = __builtin_amdgcn_mfma_f32_16x16x32_f16(pa, p8a[g_], acc[0][g_], 0, 0, 0); \
    _Pragma("unroll") for (int g_ = 0; g_ < 4; ++g_)                           \
      acc[1][g_] = __builtin_amdgcn_mfma_f32_16x16x32_f16(pa, p8b[g_], acc[1][g_], 0, 0, 0); \
  }

#define GATES_PHASE()                                                          \
  {                                                                            \
    float zb8[2][4];                                                           \
    _Pragma("unroll") for (int u_ = 0; u_ < 2; ++u_)                           \
    _Pragma("unroll") for (int g_ = 0; g_ < 4; ++g_)                           \
      zb8[u_][g_] = *reinterpret_cast<const float*>(                           \
          &smem[zb_rd + (uint32_t)((u_ * 4 + g_) * 64)]);                      \
    _Pragma("unroll") for (int u_ = 0; u_ < 2; ++u_)                           \
    _Pragma("unroll") for (int r_ = 0; r_ < 4; ++r_) {                         \
      float iv = sigf(acc[u_][0][r_] + zb8[u_][0]);                            \
      float fv = sigf(acc[u_][1][r_] + zb8[u_][1]);                            \
      float gv = tanh_f(acc[u_][2][r_] + zb8[u_][2]);                          \
      float ov = sigf(acc[u_][3][r_] + zb8[u_][3]);                            \
      float cc = fv * cf[u_][r_] + iv * gv;                                    \
      cf[u_][r_] = cc;                                                         \
      hv[u_][r_] = (_Float16)(ov * tanh_f(cc));                                \
    }                                                                          \
  }

#define H_STORE()                                                              \
  _Pragma("unroll") for (int u_ = 0; u_ < 2; ++u_)                             \
  _Pragma("unroll") for (int r_ = 0; r_ < 4; ++r_)                             \
    *reinterpret_cast<_Float16*>(&smem[h_wr + (uint32_t)(u_ * 512 + r_ * 16)]) \
        = hv[u_][r_];

// 16 blocks x 512 threads; one block per 16 batch rows; 1 block/CU.
__global__ __launch_bounds__(512, 2)
void lstm_main_k(const float* __restrict__ pulse,      // (256,1024,8)
                 const float* __restrict__ embed,      // (1,2)
                 const float* __restrict__ b_mlp,      // (2)
                 const float* __restrict__ scale_w,    // (2)
                 const float* __restrict__ scale_b,    // (2)
                 const _Float16* __restrict__ rkT,
                 const _Float16* __restrict__ WeffT,
                 const _Float16* __restrict__ WmlpT,
                 const _Float16* __restrict__ DeffH,
                 const float* __restrict__ zbias,
                 const float* __restrict__ dbias,
                 float* __restrict__ out)              // (256,35,2)
{
  __shared__ alignas(16) char smem[LDS_SZ];

  const int tid  = threadIdx.x;
  const int w    = tid >> 6;
  const int lane = tid & 63;
  const int n    = lane & 15;
  const int quad = lane >> 4;
  const int b0   = blockIdx.x * 16;

  const char* rkTb  = reinterpret_cast<const char*>(rkT);
  const char* weffb = reinterpret_cast<const char*>(WeffT);
  const char* deffb = reinterpret_cast<const char*>(DeffH);
  const char* wmlpb = reinterpret_cast<const char*>(WmlpT);
  const uint32_t gbo = (uint32_t)((w * 32 + n) * 512 + quad * 16);
  const uint32_t p8o = (uint32_t)(w * 512 + n * 16);

  h8 z8;
#pragma unroll
  for (int j = 0; j < 8; ++j) z8[j] = (_Float16)0.f;

  // ---------------- LDS init ----------------
  // zero both h parity buffers (16384 B)
  for (int i = tid; i < 1024; i += 512) {
    f4 zz; zz[0] = zz[1] = zz[2] = zz[3] = 0.f;
    *reinterpret_cast<f4*>(&smem[LB_H0 + i * 16]) = zz;
  }
  // zbias
#pragma unroll
  for (int i = 0; i < 2; ++i) {
    int e = tid + i * 512;
    int ew = e >> 7, efi = (e >> 4) & 7, en = e & 15;
    int eu = efi >> 2, eg = efi & 3;
    int col = eg * 256 + ew * 32 + eu * 16 + en;
    *reinterpret_cast<float*>(&smem[LB_ZB + e * 4]) = zbias[col];
  }
  // pool: slots 6,7 ([w][fi16][lane]*16B, fi = (s8-6)*8 + u*4 + g)
  const uint32_t pool_rd = (uint32_t)(LB_POOL + w * 16384 + lane * 16);
#pragma unroll
  for (int fi = 0; fi < 16; ++fi) {
    int s8 = 6 + (fi >> 3), u = (fi >> 2) & 1, g = fi & 3;
    *reinterpret_cast<h8*>(&smem[pool_rd + (uint32_t)(fi * 1024)]) =
        GFRAG(s8, u, g);
  }
  // register-resident weights: slots 0..2
  h8 Wreg[3][2][4];
#pragma unroll
  for (int s8 = 0; s8 < 3; ++s8)
#pragma unroll
    for (int u = 0; u < 2; ++u)
#pragma unroll
      for (int g = 0; g < 4; ++g)
        Wreg[s8][u][g] = GFRAG(s8, u, g);
  // stream buffer: prefetch slot 3 for the first step
  h8 gq[2][4];
  GQLD(3);

  // per-lane addresses (parity bit 13 flipped each step)
  uint32_t h_rd = (uint32_t)(LB_H0 + quad * 256 + n * 16);
  uint32_t h_wr = (uint32_t)(LB_H0 + 8192 + (w * 4 + (n >> 3)) * 256 +
                             quad * 64 + (n & 7) * 2);
  const uint32_t zb_rd = (uint32_t)(LB_ZB + w * 512 + n * 4);

  f4 cf[2];
#pragma unroll
  for (int u = 0; u < 2; ++u) { cf[u][0]=0.f; cf[u][1]=0.f; cf[u][2]=0.f; cf[u][3]=0.f; }

  const float* prow = pulse + (size_t)(b0 + n) * 8192;   // quad0 lanes use it

  __syncthreads();

  // ---------------- encoder: t = 0..1023 ----------------
#pragma unroll 1
  for (int t = 0; t < 1024; ++t) {
    f4 px0, px1;
    px0[0]=px0[1]=px0[2]=px0[3]=0.f; px1[0]=px1[1]=px1[2]=px1[3]=0.f;
    if (quad == 0) {
      const f4* pp = reinterpret_cast<const f4*>(prow) + t * 2;
      px0 = pp[0]; px1 = pp[1];
    }
    f4 acc[2][4];
#pragma unroll
    for (int u = 0; u < 2; ++u)
#pragma unroll
      for (int g = 0; g < 4; ++g) {
        acc[u][g][0]=0.f; acc[u][g][1]=0.f; acc[u][g][2]=0.f; acc[u][g][3]=0.f;
      }
    _Float16 hv[2][4];

    WSTEP(weffb,
      if (quad == 0) {
        pa[0] = (_Float16)px0[0]; pa[1] = (_Float16)px0[1];
        pa[2] = (_Float16)px0[2]; pa[3] = (_Float16)px0[3];
        pa[4] = (_Float16)px1[0]; pa[5] = (_Float16)px1[1];
        pa[6] = (_Float16)px1[2]; pa[7] = (_Float16)px1[3];
      }
    )

    GATES_PHASE();
    H_STORE();
    __syncthreads();
    h_rd ^= 8192u; h_wr ^= 8192u;
  }

  // ---------------- decoder ----------------
  // swap zb -> dbias
#pragma unroll
  for (int i = 0; i < 2; ++i) {
    int e = tid + i * 512;
    int ew = e >> 7, efi = (e >> 4) & 7, en = e & 15;
    int eu = efi >> 2, eg = efi & 3;
    int col = eg * 256 + ew * 32 + eu * 16 + en;
    *reinterpret_cast<float*>(&smem[LB_ZB + e * 4]) = dbias[col];
  }
  float tok0 = embed[0];
  float tok1 = embed[1];
  const float swv = (n < 2) ? scale_w[n] : 0.f;
  const float sbv = (n < 2) ? scale_b[n] : 0.f;
  const float bmv = (n < 2) ? b_mlp[n]   : 0.f;
  __syncthreads();

#pragma unroll 1
  for (int s = 0; s < 35; ++s) {
    f4 acc[2][4];
#pragma unroll
    for (int u = 0; u < 2; ++u)
#pragma unroll
      for (int g = 0; g < 4; ++g) {
        acc[u][g][0]=0.f; acc[u][g][1]=0.f; acc[u][g][2]=0.f; acc[u][g][3]=0.f;
      }
    _Float16 hv[2][4];

    WSTEP(deffb,
      if (quad == 0) {
        pa[0] = (_Float16)tok0; pa[1] = (_Float16)tok1;
      }
    )

    GATES_PHASE();
    H_STORE();
    __syncthreads();

    // pred_s = h(new) @ W_mlp + b_mlp : every wave, then shuffle -> tok regs
    {
      const uint32_t hp = h_rd ^ 8192u;   // parity just written
      f4 pf; pf[0] = bmv; pf[1] = bmv; pf[2] = bmv; pf[3] = bmv;
#pragma unroll
      for (int s8 = 0; s8 < 8; ++s8) {
        h8 hvx = *reinterpret_cast<const h8*>(&smem[hp + (uint32_t)(s8 * 1024)]);
        h8 wb = z8;
        if (n < 2)
          wb = *reinterpret_cast<const h8*>(
              wmlpb + (uint32_t)(n * 512 + s8 * 64 + quad * 16));
        pf = __builtin_amdgcn_mfma_f32_16x16x32_f16(hvx, wb, pf, 0, 0, 0);
      }
      if (w == 0 && n < 2) {
#pragma unroll
        for (int r = 0; r < 4; ++r) {
          int row = quad * 4 + r;
          out[((size_t)(b0 + row) * 35 + s) * 2 + n] = pf[r] * swv + sbv;
        }
      }
      // redistribute: quad0 lane n needs pred[row=n][e] from lane (n>>2)*16+e, reg n&3
      int srcl = (n >> 2) * 16;
      float q0 = __shfl(pf[0], srcl),     q1 = __shfl(pf[1], srcl);
      float q2 = __shfl(pf[2], srcl),     q3 = __shfl(pf[3], srcl);
      float r0 = __shfl(pf[0], srcl + 1), r1 = __shfl(pf[1], srcl + 1);
      float r2 = __shfl(pf[2], srcl + 1), r3 = __shfl(pf[3], srcl + 1);
      int rr = n & 3;
      tok0 = (rr == 0) ? q0 : (rr == 1) ? q1 : (rr == 2) ? q2 : q3;
      tok1 = (rr == 0) ? r0 : (rr == 1) ? r1 : (rr == 2) ? r2 : r3;
    }
    h_rd ^= 8192u; h_wr ^= 8192u;
  }
}

extern "C" void kernel_launch(void* const* d_in, const int* in_sizes, int n_in,
                              void* d_out, int out_size, void* d_ws, size_t ws_size,
                              hipStream_t stream) {
  const float* pulse    = (const float*)d_in[0];
  const float* bn_gamma = (const float*)d_in[1];
  const float* bn_beta  = (const float*)d_in[2];
  const float* bn_mean  = (const float*)d_in[3];
  const float* bn_var   = (const float*)d_in[4];
  const float* W_pulse  = (const float*)d_in[5];
  const float* b_pulse  = (const float*)d_in[6];
  const float* lstm_k   = (const float*)d_in[7];
  const float* lstm_rk  = (const float*)d_in[8];
  const float* lstm_b   = (const float*)d_in[9];
  const float* embed    = (const float*)d_in[10];
  const float* W_eis    = (const float*)d_in[11];
  const float* b_eis    = (const float*)d_in[12];
  const float* W_mlp    = (const float*)d_in[13];
  const float* b_mlp    = (const float*)d_in[14];
  const float* scale_w  = (const float*)d_in[15];
  const float* scale_b  = (const float*)d_in[16];

  char* ws = (char*)d_ws;
  _Float16* DeffH = (_Float16*)(ws + WS_DEFFH);
  _Float16* rkT   = (_Float16*)(ws + WS_RKT);
  _Float16* WeffT = (_Float16*)(ws + WS_WEFF);
  _Float16* WmlpT = (_Float16*)(ws + WS_WMLP);
  float*    zbias = (float*)(ws + WS_ZB);
  float*    dbias = (float*)(ws + WS_DB);

  precompute_k<<<1024, 256, 0, stream>>>(bn_gamma, bn_beta, bn_mean, bn_var,
                                         W_pulse, b_pulse, lstm_k, lstm_rk, lstm_b,
                                         W_eis, b_eis, W_mlp,
                                         rkT, WeffT, WmlpT, DeffH, zbias, dbias);
  lstm_main_k<<<16, 512, 0, stream>>>(pulse, embed, b_mlp, scale_w, scale_b,
                                      rkT, WeffT, WmlpT, DeffH, zbias, dbias,
                                      (float*)d_out);
}